// Round 4
// baseline (464.401 us; speedup 1.0000x reference)
//
#include <hip/hip_runtime.h>
#include <hip/hip_bf16.h>

// Problem constants
#define BB     8
#define HH     16
#define QLEN   256
#define DH     128
#define BSZ    16
#define MAXB   256
#define KT     64            // kv tile
#define QT     64            // q rows per block (4 waves x 16)
#define BHQ    (BB*HH*QLEN)  // 32768 rows
#define VROW   144           // padded V^T row stride in bytes (64*2 + 16)

typedef __attribute__((ext_vector_type(8))) short bf16x8;
typedef __attribute__((ext_vector_type(4))) short bf16x4;
typedef __attribute__((ext_vector_type(4))) float f32x4;

__device__ __forceinline__ unsigned pk2(float a, float b) {   // a -> low bf16, b -> high
  union { __hip_bfloat162 h; unsigned u; } c;
  c.h = __float22bfloat162_rn(make_float2(a, b));
  return c.u;
}

__device__ __forceinline__ f32x4 mfma16(bf16x4 a, bf16x4 b, f32x4 c) {
#if __has_builtin(__builtin_amdgcn_mfma_f32_16x16x16bf16_1k)
  return __builtin_amdgcn_mfma_f32_16x16x16bf16_1k(a, b, c, 0, 0, 0);
#else
  asm volatile("v_mfma_f32_16x16x16_bf16 %0, %1, %2, %0" : "+v"(c) : "v"(a), "v"(b));
  return c;
#endif
}

// Block = (qb, c, bh): 4 waves, wave owns 16 q rows. Swapped-QK^T flash attention:
//   S^T = mfma_16x16x32(A=K[kv][d], B=Q^T[d][q])  -> lane holds q=ll, kv = mt*16+lg*4+r
//   softmax lane-local (+2 shfl_xor across lg), P packed in-register (cvt_pk)
//   O^T = mfma_16x16x16(A=V^T[d][kv16], B=P^T[kv16][q]) -> lane holds q=ll, d=nj*16+lg*4+r
// Grid order: qb is the SLOW index so the 4 q-blocks sharing one KV chunk have
// bids differing by nbh (multiple of 8) -> same XCD under round-robin -> shared L2.
// K LDS: [64][128] bf16 row-major, XOR swizzle ((row&7)<<4) on 16B units.
// V LDS: transposed [128 d][64 kv] bf16, row stride 144 B, kv-offset XOR-swizzled
//        with ((d>>2)&15)<<3 (8B-granular) -> staging writes 2-way (free).
__launch_bounds__(256, 4)
__global__ void paged_attn_kernel(const float* __restrict__ qg,
                                  const float* __restrict__ kc,
                                  const float* __restrict__ vc,
                                  const int* __restrict__ bt,
                                  const int* __restrict__ sl,
                                  float* __restrict__ opart,   // [nkv][BHQ][DH] (or out if nkv==1)
                                  float* __restrict__ mpart,   // [nkv][BHQ]
                                  float* __restrict__ lpart,   // [nkv][BHQ]
                                  int nkv) {
  __shared__ __align__(16) char kls[KT * DH * 2];   // 16 KiB
  __shared__ __align__(16) char vls[DH * VROW];     // 18 KiB
  __shared__ int btab[MAXB];                        // 1 KiB

  const int tid  = threadIdx.x;
  const int wave = tid >> 6;
  const int lane = tid & 63;
  const int lg   = lane >> 4;   // 16-lane group 0..3
  const int ll   = lane & 15;

  const int bid = blockIdx.x;
  const int nbh = BB * HH * nkv;   // 128 or 256, both % 8 == 0
  const int qb  = bid / nbh;       // SLOW index: q-siblings share XCD
  const int rem = bid % nbh;
  const int c   = rem % nkv;
  const int bh  = rem / nkv;
  const int b   = bh >> 4;      // H = 16
  const int h   = bh & 15;

  const int seq = sl[b];
  const int nt  = (seq + KT - 1) / KT;
  const int per = (nt + nkv - 1) / nkv;
  const int t0  = c * per;
  const int t1  = (t0 + per < nt) ? (t0 + per) : nt;

  if (tid < MAXB) btab[tid] = bt[b * MAXB + tid];

  // ---- Q fragments (B-operand of S^T): lane provides col q = qbase+ll, k-rows d ----
  const float qscale = 0.08838834764831845f * 1.4426950408889634f;  // 1/sqrt(128) * log2(e)
  const int qbase = qb * QT + wave * 16;
  bf16x8 qf[4];
  {
    const float* qr = qg + ((size_t)bh * QLEN + qbase + ll) * DH;
#pragma unroll
    for (int ks = 0; ks < 4; ++ks) {
      const float4 a  = *(const float4*)(qr + ks * 32 + lg * 8);
      const float4 bv = *(const float4*)(qr + ks * 32 + lg * 8 + 4);
      union { bf16x8 v; unsigned u[4]; } w;
      w.u[0] = pk2(a.x * qscale,  a.y * qscale);
      w.u[1] = pk2(a.z * qscale,  a.w * qscale);
      w.u[2] = pk2(bv.x * qscale, bv.y * qscale);
      w.u[3] = pk2(bv.z * qscale, bv.w * qscale);
      qf[ks] = w.v;
    }
  }

  f32x4 accT[8];   // O^T: lane holds q=qbase+ll, d = nj*16 + lg*4 + r
#pragma unroll
  for (int nj = 0; nj < 8; ++nj) accT[nj] = (f32x4){0.f, 0.f, 0.f, 0.f};
  float mrow = -1e30f, lrow = 0.f;

  __syncthreads();  // btab visible

  for (int t = t0; t < t1; ++t) {
    const int kv0 = t * KT;
    __syncthreads();  // previous tile's LDS readers done

    // ---- stage K: 64 rows x 16 b128-chunks = 1024 slots / 256 thr ----
#pragma unroll
    for (int i = 0; i < 4; ++i) {
      const int slot = i * 256 + tid;
      const int row  = slot >> 4;       // kv within tile
      const int c16  = slot & 15;       // 16B chunk along d (8 bf16)
      const int kv   = kv0 + row;
      const int phys = btab[kv >> 4];
      const size_t gb = (((size_t)phys * HH + h) * BSZ + (kv & 15)) * DH + c16 * 8;
      const float4 f0 = *(const float4*)(kc + gb);
      const float4 f1 = *(const float4*)(kc + gb + 4);
      union { uint4 u4; unsigned u[4]; } w;
      w.u[0] = pk2(f0.x, f0.y); w.u[1] = pk2(f0.z, f0.w);
      w.u[2] = pk2(f1.x, f1.y); w.u[3] = pk2(f1.z, f1.w);
      const int kb = (row * 256 + c16 * 16) ^ ((row & 7) << 4);
      *(uint4*)(kls + kb) = w.u4;
    }
    // ---- stage V^T: 32 kv-pairs x 32 float4-cols = 1024 slots / 256 thr ----
#pragma unroll
    for (int i = 0; i < 4; ++i) {
      const int slot = i * 256 + tid;
      const int kvp  = slot >> 5;       // kv pair (2*kvp, 2*kvp+1)
      const int col4 = slot & 31;
      const int kv   = kv0 + kvp * 2;
      const int phys = btab[kv >> 4];   // kv even: kv,kv+1 in same physical block
      const size_t gb = (((size_t)phys * HH + h) * BSZ + (kv & 15)) * DH + col4 * 4;
      const float4 va = *(const float4*)(vc + gb);
      const float4 vb = *(const float4*)(vc + gb + DH);
      const float aa[4] = {va.x, va.y, va.z, va.w};
      const float bb[4] = {vb.x, vb.y, vb.z, vb.w};
#pragma unroll
      for (int jj = 0; jj < 4; ++jj) {
        const int d  = col4 * 4 + jj;
        const int xo = ((d >> 2) & 15) << 3;             // 8B-granular row swizzle
        *(unsigned*)(vls + d * VROW + ((kvp * 4) ^ xo)) = pk2(aa[jj], bb[jj]);
      }
    }
    __syncthreads();

    // ---- S^T = K · Q^T : per mt (16 kv rows) ----
    f32x4 s[4];
#pragma unroll
    for (int mt = 0; mt < 4; ++mt) {
      f32x4 acc = (f32x4){0.f, 0.f, 0.f, 0.f};
      const int krow = mt * 16 + ll;
      const int kbase = krow * 256;
      const int ksw  = (krow & 7) << 4;
#pragma unroll
      for (int ks = 0; ks < 4; ++ks) {
        const bf16x8 kf = *(const bf16x8*)(kls + ((kbase + ks * 64 + lg * 16) ^ ksw));
        acc = __builtin_amdgcn_mfma_f32_16x16x32_bf16(kf, qf[ks], acc, 0, 0, 0);
      }
      s[mt] = acc;
    }

    // ---- online softmax: lane owns q-row (q=qbase+ll), 16 scores kv=mt*16+lg*4+r ----
    if (kv0 + KT > seq) {
#pragma unroll
      for (int mt = 0; mt < 4; ++mt)
#pragma unroll
        for (int r = 0; r < 4; ++r) {
          const int kvg = kv0 + mt * 16 + lg * 4 + r;
          if (kvg >= seq) s[mt][r] = -1e30f;
        }
    }
    float mx = s[0][0];
#pragma unroll
    for (int mt = 0; mt < 4; ++mt)
#pragma unroll
      for (int r = 0; r < 4; ++r) mx = fmaxf(mx, s[mt][r]);
    mx = fmaxf(mx, __shfl_xor(mx, 16));
    mx = fmaxf(mx, __shfl_xor(mx, 32));
    const float mnew  = fmaxf(mrow, mx);
    const float alpha = exp2f(mrow - mnew);
    mrow = mnew;
    float rs = 0.f;
#pragma unroll
    for (int mt = 0; mt < 4; ++mt)
#pragma unroll
      for (int r = 0; r < 4; ++r) {
        s[mt][r] = exp2f(s[mt][r] - mnew);   // in-place: s -> p
        rs += s[mt][r];
      }
    rs += __shfl_xor(rs, 16);
    rs += __shfl_xor(rs, 32);
    lrow = lrow * alpha + rs;
#pragma unroll
    for (int nj = 0; nj < 8; ++nj) {
      accT[nj][0] *= alpha; accT[nj][1] *= alpha;
      accT[nj][2] *= alpha; accT[nj][3] *= alpha;
    }

    // ---- pack P^T into B-frags for 16x16x16 (k-rows lg*4+r == held layout) ----
    bf16x4 pb[4];
#pragma unroll
    for (int mt = 0; mt < 4; ++mt) {
      union { bf16x4 v; unsigned u[2]; } w;
      w.u[0] = pk2(s[mt][0], s[mt][1]);
      w.u[1] = pk2(s[mt][2], s[mt][3]);
      pb[mt] = w.v;
    }

    // ---- O^T += V^T · P^T ----
#pragma unroll
    for (int nj = 0; nj < 8; ++nj) {
      const int d  = nj * 16 + ll;
      const int xo = ((d >> 2) & 15) << 3;
      const char* vb = vls + d * VROW;
#pragma unroll
      for (int mt = 0; mt < 4; ++mt) {
        const bf16x4 va = *(const bf16x4*)(vb + ((lg * 8 + mt * 32) ^ xo));
        accT[nj] = mfma16(va, pb[mt], accT[nj]);
      }
    }
  }

  // ---- epilogue: lane writes q-row qbase+ll, d = nj*16+lg*4 .. +3 (float4) ----
  const int grow = bh * QLEN + qbase + ll;
  if (nkv == 1) {
    const float inv = 1.0f / lrow;
    float* orow = opart + (size_t)grow * DH;
#pragma unroll
    for (int nj = 0; nj < 8; ++nj) {
      f32x4 v = accT[nj];
      v[0] *= inv; v[1] *= inv; v[2] *= inv; v[3] *= inv;
      *(f32x4*)(orow + nj * 16 + lg * 4) = v;
    }
  } else {
    float* orow = opart + ((size_t)c * BHQ + grow) * DH;
#pragma unroll
    for (int nj = 0; nj < 8; ++nj)
      *(f32x4*)(orow + nj * 16 + lg * 4) = accT[nj];   // unnormalized
    if (lg == 0) {
      mpart[c * BHQ + grow] = mrow;
      lpart[c * BHQ + grow] = lrow;
    }
  }
}

__global__ void combine_kernel(const float* __restrict__ op,
                               const float* __restrict__ mp,
                               const float* __restrict__ lp,
                               float* __restrict__ out, int nkv) {
  const int idx = blockIdx.x * 256 + threadIdx.x;  // float4 index over BHQ*DH/4
  const int row = idx >> 5;                        // 32 float4 per row
  float M = -1e30f;
  for (int cc = 0; cc < nkv; ++cc) M = fmaxf(M, mp[cc * BHQ + row]);
  float den = 0.f;
  float4 o = make_float4(0.f, 0.f, 0.f, 0.f);
  for (int cc = 0; cc < nkv; ++cc) {
    const float w = exp2f(mp[cc * BHQ + row] - M);
    den += lp[cc * BHQ + row] * w;
    const float4 v = ((const float4*)op)[(size_t)cc * (BHQ * (DH / 4)) + idx];
    o.x += w * v.x; o.y += w * v.y; o.z += w * v.z; o.w += w * v.w;
  }
  const float inv = 1.0f / den;
  ((float4*)out)[idx] = make_float4(o.x * inv, o.y * inv, o.z * inv, o.w * inv);
}

extern "C" void kernel_launch(void* const* d_in, const int* in_sizes, int n_in,
                              void* d_out, int out_size, void* d_ws, size_t ws_size,
                              hipStream_t stream) {
  const float* q  = (const float*)d_in[0];
  const float* kc = (const float*)d_in[1];
  const float* vc = (const float*)d_in[2];
  const int* bt   = (const int*)d_in[3];
  const int* sl   = (const int*)d_in[4];
  float* out = (float*)d_out;

  const size_t perchunk = (size_t)BHQ * DH * sizeof(float) + (size_t)BHQ * 2 * sizeof(float);
  int nkv = 1;
  if (ws_size >= 2 * perchunk) nkv = 2;   // grid 1024 = 4 resident blocks/CU

  float* op = (nkv == 1) ? out : (float*)d_ws;
  float* mp = (float*)d_ws + (size_t)nkv * BHQ * DH;
  float* lp = mp + (size_t)nkv * BHQ;

  paged_attn_kernel<<<dim3(BB * HH * 4 * nkv), dim3(256), 0, stream>>>(q, kc, vc, bt, sl, op, mp, lp, nkv);
  if (nkv > 1)
    combine_kernel<<<dim3(BHQ * DH / 4 / 256), dim3(256), 0, stream>>>(op, mp, lp, out, nkv);
}

// Round 5
// 150.747 us; speedup vs baseline: 3.0807x; 3.0807x over previous
//
#include <hip/hip_runtime.h>
#include <hip/hip_bf16.h>

// Problem constants
#define BB     8
#define HH     16
#define QLEN   256
#define DH     128
#define BSZ    16
#define MAXB   256
#define KT     64            // kv tile
#define BHQ    (BB*HH*QLEN)  // 32768 rows
#define VROW   144           // padded V^T row stride in bytes (64*2 + 16)

typedef __attribute__((ext_vector_type(8))) short bf16x8;
typedef __attribute__((ext_vector_type(4))) short bf16x4;
typedef __attribute__((ext_vector_type(4))) float f32x4;

__device__ __forceinline__ unsigned pk2(float a, float b) {   // a -> low bf16, b -> high
  union { __hip_bfloat162 h; unsigned u; } c;
  c.h = __float22bfloat162_rn(make_float2(a, b));
  return c.u;
}

__device__ __forceinline__ f32x4 mfma16(bf16x4 a, bf16x4 b, f32x4 c) {
#if __has_builtin(__builtin_amdgcn_mfma_f32_16x16x16bf16_1k)
  return __builtin_amdgcn_mfma_f32_16x16x16bf16_1k(a, b, c, 0, 0, 0);
#else
  asm volatile("v_mfma_f32_16x16x16_bf16 %0, %1, %2, %0" : "+v"(c) : "v"(a), "v"(b));
  return c;
#endif
}

// Block = (bh, c): 512 thr / 8 waves; wave owns 32 q rows (2 M-tiles of 16).
// All 256 q rows in one block -> each staged KV byte feeds full Q (LDS reuse,
// no cache-dependent sibling sharing). Swapped-QK^T flash attention:
//   S^T = mfma_16x16x32(A=K[kv][d], B=Q^T[d][q])  -> lane q=ll, kv=mt*16+lg*4+r
//   softmax lane-local (+2 shfl_xor), P packed in-register (cvt_pk)
//   O^T = mfma_16x16x16(A=V^T[d][kv16], B=P^T[kv16][q]) -> lane q=ll, d=nj*16+lg*4+r
// LDS double-buffered; ONE barrier per tile; tile t+1 global loads issued
// AFTER the barrier (so the barrier's vmcnt drain can't flush them), converted
// + written at the top of iteration t+1 (latency hides under compute of t).
// K LDS: [64][128] bf16 row-major, XOR swizzle ((row&7)<<4) on 16B units.
// V LDS: [128 d][64 kv] bf16 transposed, row stride 144 B, kv-offset XOR ((d>>2)&15)<<3.
__launch_bounds__(512, 2)
__global__ void paged_attn_kernel(const float* __restrict__ qg,
                                  const float* __restrict__ kc,
                                  const float* __restrict__ vc,
                                  const int* __restrict__ bt,
                                  const int* __restrict__ sl,
                                  float* __restrict__ opart,   // [nkv][BHQ][DH] (or out if nkv==1)
                                  float* __restrict__ mpart,   // [nkv][BHQ]
                                  float* __restrict__ lpart,   // [nkv][BHQ]
                                  int nkv) {
  __shared__ __align__(16) char kls[2][KT * DH * 2];   // 2 x 16 KiB
  __shared__ __align__(16) char vls[2][DH * VROW];     // 2 x 18 KiB
  __shared__ int btab[MAXB];                           // 1 KiB

  const int tid  = threadIdx.x;
  const int wave = tid >> 6;    // 0..7
  const int lane = tid & 63;
  const int lg   = lane >> 4;   // 16-lane group 0..3
  const int ll   = lane & 15;

  const int bid = blockIdx.x;
  const int c   = bid % nkv;
  const int bh  = bid / nkv;
  const int b   = bh >> 4;      // H = 16
  const int h   = bh & 15;

  const int seq = sl[b];
  const int nt  = (seq + KT - 1) / KT;
  const int per = (nt + nkv - 1) / nkv;
  const int t0  = c * per;
  const int t1  = (t0 + per < nt) ? (t0 + per) : nt;

  if (tid < MAXB) btab[tid] = bt[b * MAXB + tid];
  __syncthreads();  // btab visible

  // ---- prefetch registers for one tile ----
  float4 kreg[2][2];   // K slot i: rows (i*512+tid)>>4, 16B chunk (i*512+tid)&15
  float4 vreg[2][2];   // V slot i: kv pair (i*512+tid)>>5, float4 col (i*512+tid)&31

#define ISSUE_LOADS(KV0)                                                        \
  {                                                                             \
    _Pragma("unroll")                                                           \
    for (int i = 0; i < 2; ++i) {                                               \
      const int slot = i * 512 + tid;                                           \
      const int row = slot >> 4, c16 = slot & 15;                               \
      const int kv = (KV0) + row;                                               \
      const int phys = btab[kv >> 4];                                           \
      const size_t gb = (((size_t)phys * HH + h) * BSZ + (kv & 15)) * DH + c16 * 8; \
      kreg[i][0] = *(const float4*)(kc + gb);                                   \
      kreg[i][1] = *(const float4*)(kc + gb + 4);                               \
    }                                                                           \
    _Pragma("unroll")                                                           \
    for (int i = 0; i < 2; ++i) {                                               \
      const int slot = i * 512 + tid;                                           \
      const int kvp = slot >> 5, col4 = slot & 31;                              \
      const int kv = (KV0) + kvp * 2;                                           \
      const int phys = btab[kv >> 4];                                           \
      const size_t gb = (((size_t)phys * HH + h) * BSZ + (kv & 15)) * DH + col4 * 4; \
      vreg[i][0] = *(const float4*)(vc + gb);                                   \
      vreg[i][1] = *(const float4*)(vc + gb + DH);                              \
    }                                                                           \
  }

  if (t0 < t1) ISSUE_LOADS(t0 * KT)   // prologue: tile t0 in flight

  // ---- Q fragments (B-operand of S^T), scale*log2(e) folded in ----
  const float qscale = 0.08838834764831845f * 1.4426950408889634f;
  const int qbase = wave * 32;
  bf16x8 qf[2][4];
#pragma unroll
  for (int mi = 0; mi < 2; ++mi) {
    const float* qr = qg + ((size_t)bh * QLEN + qbase + mi * 16 + ll) * DH;
#pragma unroll
    for (int ks = 0; ks < 4; ++ks) {
      const float4 a  = *(const float4*)(qr + ks * 32 + lg * 8);
      const float4 bv = *(const float4*)(qr + ks * 32 + lg * 8 + 4);
      union { bf16x8 v; unsigned u[4]; } w;
      w.u[0] = pk2(a.x * qscale,  a.y * qscale);
      w.u[1] = pk2(a.z * qscale,  a.w * qscale);
      w.u[2] = pk2(bv.x * qscale, bv.y * qscale);
      w.u[3] = pk2(bv.z * qscale, bv.w * qscale);
      qf[mi][ks] = w.v;
    }
  }

  f32x4 accT[2][8];    // O^T: lane q = qbase+mi*16+ll, d = nj*16 + lg*4 + r
#pragma unroll
  for (int mi = 0; mi < 2; ++mi)
#pragma unroll
    for (int nj = 0; nj < 8; ++nj) accT[mi][nj] = (f32x4){0.f, 0.f, 0.f, 0.f};
  float mrow[2] = {-1e30f, -1e30f}, lrow[2] = {0.f, 0.f};

  for (int t = t0; t < t1; ++t) {
    const int kv0 = t * KT;
    const int bb  = t & 1;

    // ---- convert prefetched fp32 -> bf16, write LDS buf bb (vmcnt waits here) ----
#pragma unroll
    for (int i = 0; i < 2; ++i) {
      const int slot = i * 512 + tid;
      const int row = slot >> 4, c16 = slot & 15;
      union { uint4 u4; unsigned u[4]; } w;
      w.u[0] = pk2(kreg[i][0].x, kreg[i][0].y);
      w.u[1] = pk2(kreg[i][0].z, kreg[i][0].w);
      w.u[2] = pk2(kreg[i][1].x, kreg[i][1].y);
      w.u[3] = pk2(kreg[i][1].z, kreg[i][1].w);
      const int kb = (row * 256 + c16 * 16) ^ ((row & 7) << 4);
      *(uint4*)(kls[bb] + kb) = w.u4;
    }
#pragma unroll
    for (int i = 0; i < 2; ++i) {
      const int slot = i * 512 + tid;
      const int kvp = slot >> 5, col4 = slot & 31;
      const float* aa = (const float*)&vreg[i][0];
      const float* bp = (const float*)&vreg[i][1];
#pragma unroll
      for (int jj = 0; jj < 4; ++jj) {
        const int d  = col4 * 4 + jj;
        const int xo = ((d >> 2) & 15) << 3;
        *(unsigned*)(vls[bb] + d * VROW + ((kvp * 4) ^ xo)) = pk2(aa[jj], bp[jj]);
      }
    }

    __syncthreads();  // buf bb ready; all waves done computing tile t-1

    // ---- issue tile t+1 loads AFTER barrier (not drained by it) ----
    if (t + 1 < t1) ISSUE_LOADS((t + 1) * KT)

    // ---- S^T = K · Q^T ----
    f32x4 s[2][4];
#pragma unroll
    for (int mt = 0; mt < 4; ++mt) {
      const int krow  = mt * 16 + ll;
      const int kbase = krow * 256;
      const int ksw   = (krow & 7) << 4;
      bf16x8 kf[4];
#pragma unroll
      for (int ks = 0; ks < 4; ++ks)
        kf[ks] = *(const bf16x8*)(kls[bb] + ((kbase + ks * 64 + lg * 16) ^ ksw));
      s[0][mt] = (f32x4){0.f, 0.f, 0.f, 0.f};
      s[1][mt] = (f32x4){0.f, 0.f, 0.f, 0.f};
#pragma unroll
      for (int ks = 0; ks < 4; ++ks)
#pragma unroll
        for (int mi = 0; mi < 2; ++mi)
          s[mi][mt] = __builtin_amdgcn_mfma_f32_16x16x32_bf16(kf[ks], qf[mi][ks], s[mi][mt], 0, 0, 0);
    }

    // ---- online softmax: lane owns q-row, 16 scores kv = mt*16+lg*4+r ----
    const bool tail = (kv0 + KT > seq);
    bf16x4 pb[2][4];
#pragma unroll
    for (int mi = 0; mi < 2; ++mi) {
      if (tail) {
#pragma unroll
        for (int mt = 0; mt < 4; ++mt)
#pragma unroll
          for (int r = 0; r < 4; ++r) {
            const int kvg = kv0 + mt * 16 + lg * 4 + r;
            if (kvg >= seq) s[mi][mt][r] = -1e30f;
          }
      }
      float mx = s[mi][0][0];
#pragma unroll
      for (int mt = 0; mt < 4; ++mt)
#pragma unroll
        for (int r = 0; r < 4; ++r) mx = fmaxf(mx, s[mi][mt][r]);
      mx = fmaxf(mx, __shfl_xor(mx, 16));
      mx = fmaxf(mx, __shfl_xor(mx, 32));
      const float mnew  = fmaxf(mrow[mi], mx);
      const float alpha = exp2f(mrow[mi] - mnew);
      mrow[mi] = mnew;
      float rs = 0.f;
#pragma unroll
      for (int mt = 0; mt < 4; ++mt)
#pragma unroll
        for (int r = 0; r < 4; ++r) {
          s[mi][mt][r] = exp2f(s[mi][mt][r] - mnew);
          rs += s[mi][mt][r];
        }
      rs += __shfl_xor(rs, 16);
      rs += __shfl_xor(rs, 32);
      lrow[mi] = lrow[mi] * alpha + rs;
#pragma unroll
      for (int nj = 0; nj < 8; ++nj) {
        accT[mi][nj][0] *= alpha; accT[mi][nj][1] *= alpha;
        accT[mi][nj][2] *= alpha; accT[mi][nj][3] *= alpha;
      }
#pragma unroll
      for (int mt = 0; mt < 4; ++mt) {
        union { bf16x4 v; unsigned u[2]; } w;
        w.u[0] = pk2(s[mi][mt][0], s[mi][mt][1]);
        w.u[1] = pk2(s[mi][mt][2], s[mi][mt][3]);
        pb[mi][mt] = w.v;
      }
    }

    // ---- O^T += V^T · P^T ----
#pragma unroll
    for (int nj = 0; nj < 8; ++nj) {
      const int d  = nj * 16 + ll;
      const int xo = ((d >> 2) & 15) << 3;
      const char* vb = vls[bb] + d * VROW;
#pragma unroll
      for (int mt = 0; mt < 4; ++mt) {
        const bf16x4 va = *(const bf16x4*)(vb + ((lg * 8 + mt * 32) ^ xo));
#pragma unroll
        for (int mi = 0; mi < 2; ++mi)
          accT[mi][nj] = mfma16(va, pb[mi][mt], accT[mi][nj]);
      }
    }
  }

  // ---- epilogue: lane writes q-row, d = nj*16+lg*4 .. +3 (float4) ----
#pragma unroll
  for (int mi = 0; mi < 2; ++mi) {
    const int grow = bh * QLEN + qbase + mi * 16 + ll;
    if (nkv == 1) {
      const float inv = 1.0f / lrow[mi];
      float* orow = opart + (size_t)grow * DH;
#pragma unroll
      for (int nj = 0; nj < 8; ++nj) {
        f32x4 v = accT[mi][nj];
        v[0] *= inv; v[1] *= inv; v[2] *= inv; v[3] *= inv;
        *(f32x4*)(orow + nj * 16 + lg * 4) = v;
      }
    } else {
      float* orow = opart + ((size_t)c * BHQ + grow) * DH;
#pragma unroll
      for (int nj = 0; nj < 8; ++nj)
        *(f32x4*)(orow + nj * 16 + lg * 4) = accT[mi][nj];   // unnormalized
      if (lg == 0) {
        mpart[c * BHQ + grow] = mrow[mi];
        lpart[c * BHQ + grow] = lrow[mi];
      }
    }
  }
}

__global__ void combine_kernel(const float* __restrict__ op,
                               const float* __restrict__ mp,
                               const float* __restrict__ lp,
                               float* __restrict__ out, int nkv) {
  const int idx = blockIdx.x * 256 + threadIdx.x;  // float4 index over BHQ*DH/4
  const int row = idx >> 5;                        // 32 float4 per row
  float M = -1e30f;
  for (int cc = 0; cc < nkv; ++cc) M = fmaxf(M, mp[cc * BHQ + row]);
  float den = 0.f;
  float4 o = make_float4(0.f, 0.f, 0.f, 0.f);
  for (int cc = 0; cc < nkv; ++cc) {
    const float w = exp2f(mp[cc * BHQ + row] - M);
    den += lp[cc * BHQ + row] * w;
    const float4 v = ((const float4*)op)[(size_t)cc * (BHQ * (DH / 4)) + idx];
    o.x += w * v.x; o.y += w * v.y; o.z += w * v.z; o.w += w * v.w;
  }
  const float inv = 1.0f / den;
  ((float4*)out)[idx] = make_float4(o.x * inv, o.y * inv, o.z * inv, o.w * inv);
}

extern "C" void kernel_launch(void* const* d_in, const int* in_sizes, int n_in,
                              void* d_out, int out_size, void* d_ws, size_t ws_size,
                              hipStream_t stream) {
  const float* q  = (const float*)d_in[0];
  const float* kc = (const float*)d_in[1];
  const float* vc = (const float*)d_in[2];
  const int* bt   = (const int*)d_in[3];
  const int* sl   = (const int*)d_in[4];
  float* out = (float*)d_out;

  const size_t perchunk = (size_t)BHQ * DH * sizeof(float) + (size_t)BHQ * 2 * sizeof(float);
  int nkv = 1;
  if (ws_size >= 4 * perchunk) nkv = 4;        // 512 blocks -> all CUs busy
  else if (ws_size >= 2 * perchunk) nkv = 2;

  float* op = (nkv == 1) ? out : (float*)d_ws;
  float* mp = (float*)d_ws + (size_t)nkv * BHQ * DH;
  float* lp = mp + (size_t)nkv * BHQ;

  paged_attn_kernel<<<dim3(BB * HH * nkv), dim3(512), 0, stream>>>(q, kc, vc, bt, sl, op, mp, lp, nkv);
  if (nkv > 1)
    combine_kernel<<<dim3(BHQ * DH / 4 / 256), dim3(256), 0, stream>>>(op, mp, lp, out, nkv);
}